// Round 2
// baseline (487.390 us; speedup 1.0000x reference)
//
#include <hip/hip_runtime.h>
#include <math.h>

// Problem constants (from setup_inputs)
#define N_DET 512
#define K_ANN 100
#define MH    28
#define MW    28
#define NPIX  (MH * MW)     // 784
#define IMH   800
#define IMW   800
#define IOU_THRESH 0.5f
#define EPS_F 1e-7f

#define BLK_PER_DET 8
#define THREADS     128
#define PX_PER_BLK  98      // 8 * 98 = 784, exact
#define GRID        (N_DET * BLK_PER_DET)   // 4096 blocks = 8192 waves = 32/CU (full residency)

// ws layout (first 12 bytes zeroed each launch):
//   wsi[0] : valid-detection count (int)
//   wsf[1] : running |diff| sum (float)
//   wsi[2] : blocks-done counter (int) -> last block finalizes out[0]

// Single fused kernel. Block b: det n = b>>3, pixel-slice sub = b&7.
//   phase 1: wave 0 redundantly computes argmax IOU over 100 annotations
//            (deterministic: every block of det n gets the identical result)
//   phase 2: if max_iou >= 0.5, 98 lanes each do ONE bilinear pixel
//            (5 independent gathers issued together -> depth-1 latency)
//   phase 3: last-done block finalizes via device-scope atomics.
__global__ __launch_bounds__(THREADS) void maskloss_fused(
    const float* __restrict__ det,    // (512,4) x1,y1,x2,y2
    const float* __restrict__ masks,  // (512,28,28,100)
    const float* __restrict__ ann,    // (100,4)
    const float* __restrict__ mt,     // (100,800,800)
    int*   __restrict__ wsi,
    float* __restrict__ wsf,
    float* __restrict__ out)
{
    __shared__ float s_iou;
    __shared__ int   s_k;
    __shared__ float wsum[2];

    const int b   = blockIdx.x;
    const int n   = b >> 3;
    const int sub = b & 7;
    const int tid = threadIdx.x;

    const float4 d4 = ((const float4*)det)[n];
    const float dx1 = d4.x, dy1 = d4.y, dx2 = d4.z, dy2 = d4.w;

    // ---- phase 1: argmax IOU on wave 0 (lanes handle k and k+64) ----
    if (tid < 64) {
        const float darea = (dx2 - dx1) * (dy2 - dy1);
        float best = -1.0f;
        int   bidx = 0x7FFFFFFF;
        for (int k = tid; k < K_ANN; k += 64) {   // k then k+64: strict '>' keeps smaller idx on tie
            const float4 a4 = ((const float4*)ann)[k];
            const float area_k = (a4.z - a4.x) * (a4.w - a4.y);
            float iw = fminf(dx2, a4.z) - fmaxf(dx1, a4.x);
            float ih = fminf(dy2, a4.w) - fmaxf(dy1, a4.y);
            iw = fmaxf(iw, 0.0f);
            ih = fmaxf(ih, 0.0f);
            const float inter = iw * ih;
            const float ua = darea + area_k - inter;
            const float iou = inter / fmaxf(ua, EPS_F);
            if (iou > best) { best = iou; bidx = k; }
        }
        // 64-lane butterfly argmax; ties -> smaller index (jnp.argmax semantics)
        for (int m = 32; m > 0; m >>= 1) {
            const float ov = __shfl_xor(best, m);
            const int   oi = __shfl_xor(bidx, m);
            if (ov > best || (ov == best && oi < bidx)) { best = ov; bidx = oi; }
        }
        if (tid == 0) { s_iou = best; s_k = bidx; }
    }
    __syncthreads();

    const bool valid = (s_iou >= IOU_THRESH);   // block-uniform
    const int  k     = s_k;

    // ---- phase 2: pixel loss, ONE pixel per lane ----
    if (valid) {
        // boxes = [y1/H, x1/W, y2/H, x2/W] — keep exact FP form of the verified kernel
        const float by1 = dy1 / (float)IMH;
        const float bx1 = dx1 / (float)IMW;
        const float by2 = dy2 / (float)IMH;
        const float bx2 = dx2 / (float)IMW;

        const float* __restrict__ img = mt    + (size_t)k * (IMH * IMW);
        const float* __restrict__ msk = masks + (size_t)n * (NPIX * K_ANN) + k;

        float local = 0.0f;
        if (tid < PX_PER_BLK) {
            const int p = sub * PX_PER_BLK + tid;
            const int i = p / MW;
            const int j = p - i * MW;
            const float gy = (float)i * (1.0f / (float)(MH - 1));
            const float gx = (float)j * (1.0f / (float)(MW - 1));
            const float in_y = (by1 + (by2 - by1) * gy) * (float)(IMH - 1);
            const float in_x = (bx1 + (bx2 - bx1) * gx) * (float)(IMW - 1);
            const bool vy = (in_y >= 0.0f) && (in_y <= (float)(IMH - 1));
            const bool vx = (in_x >= 0.0f) && (in_x <= (float)(IMW - 1));
            const float y0f = floorf(in_y);
            const float x0f = floorf(in_x);
            const float yf = in_y - y0f;
            const float xf = in_x - x0f;
            int y0i = (int)y0f;
            int x0i = (int)x0f;
            y0i = min(max(y0i, 0), IMH - 1);
            x0i = min(max(x0i, 0), IMW - 1);
            const int y1i = min(y0i + 1, IMH - 1);
            const int x1i = min(x0i + 1, IMW - 1);

            // all 5 loads independent — compiler issues them together, one vmcnt wait
            const float msel = msk[(size_t)p * K_ANN];   // masks[n,i,j,k], stride-100 gather
            const float v00 = img[y0i * IMW + x0i];
            const float v01 = img[y0i * IMW + x1i];
            const float v10 = img[y1i * IMW + x0i];
            const float v11 = img[y1i * IMW + x1i];
            const float top = v00 + (v01 - v00) * xf;
            const float bot = v10 + (v11 - v10) * xf;
            float outv = top + (bot - top) * yf;
            outv = (vy && vx) ? outv : 0.0f;
            local = fabsf(msel - outv);
        }

        // 64-lane shuffle reduce, then cross-wave (2 waves) via LDS
        for (int off = 32; off > 0; off >>= 1)
            local += __shfl_down(local, off);
        const int wave = tid >> 6;
        const int lane = tid & 63;
        if (lane == 0) wsum[wave] = local;
        __syncthreads();
        if (tid == 0) {
            atomicAdd(&wsf[1], wsum[0] + wsum[1]);
            if (sub == 0) atomicAdd(&wsi[0], 1);   // once per valid detection
        }
    }

    // ---- phase 3: last-done block finalizes (device-scope atomics only) ----
    __threadfence();
    if (tid == 0) {
        if (atomicAdd(&wsi[2], 1) == GRID - 1) {
            const int   c = atomicAdd(&wsi[0], 0);        // coherent read-back
            const float s = atomicAdd(&wsf[1], 0.0f);     // coherent read-back
            out[0] = s / fmaxf((float)c * (float)NPIX, 1.0f);
        }
    }
}

extern "C" void kernel_launch(void* const* d_in, const int* in_sizes, int n_in,
                              void* d_out, int out_size, void* d_ws, size_t ws_size,
                              hipStream_t stream) {
    const float* det   = (const float*)d_in[0];  // detections (1,512,4)
    const float* masks = (const float*)d_in[1];  // masks (1,512,28,28,100)
    const float* ann   = (const float*)d_in[2];  // annotations (1,100,4)
    const float* mt    = (const float*)d_in[3];  // masks_target (1,100,800,800)
    float* out = (float*)d_out;
    int*   wsi = (int*)d_ws;
    float* wsf = (float*)d_ws;

    // ws is poisoned to 0xAA before every timed launch — zero count, sum, done.
    hipMemsetAsync(d_ws, 0, 3 * sizeof(int), stream);

    maskloss_fused<<<GRID, THREADS, 0, stream>>>(det, masks, ann, mt, wsi, wsf, out);
}